// Round 6
// baseline (370.415 us; speedup 1.0000x reference)
//
#include <hip/hip_runtime.h>
#include <math.h>

// ---------------------------------------------------------------------------
// MultiheadAttention B=2,S=2048,D=1024,H=16,HD=64. I/O fp32; internal fp16 MFMA.
//   0) cvt: q,k,v,WQ..WO fp32 -> fp16 (once)
//   1) gemm_qkv (m97 staging, direct-store epilogue):
//      Q fp16 [B,H,S,64] pre-scaled by 0.125*log2e, K fp16 [B,H,S,64],
//      V fp16 transposed [B,H,64,S]
//   2) attn: transposed scores S^T = K Q^T (exp2-domain online softmax),
//      DOUBLE-BUFFERED global_load_lds K/V staging, 1 barrier/tile -> AO fp16
//   3) gemm_o: AO @ WO^T + b -> d_out fp32
// ---------------------------------------------------------------------------

typedef _Float16 h8 __attribute__((ext_vector_type(8)));
typedef _Float16 h4 __attribute__((ext_vector_type(4)));
typedef float f4 __attribute__((ext_vector_type(4)));

#define MFMA16(a, b, c) __builtin_amdgcn_mfma_f32_16x16x32_f16((a), (b), (c), 0, 0, 0)
#define EXP2F(x) __builtin_amdgcn_exp2f(x)   // v_exp_f32 = 2^x (glibc-safe name)

static constexpr int Bn = 2, Sn = 2048, Dn = 1024, Hn = 16, HDn = 64;
static constexpr int Mn = Bn * Sn;   // 4096
static constexpr int Kn = Dn;        // 1024
static constexpr int Nn = Dn;        // 1024
static constexpr int LDP = 72;       // attn P-slab stride (64 + 8 pad)
static constexpr float LOG2E = 1.4426950408889634f;

__device__ __forceinline__ void gload_lds16(const _Float16* g, _Float16* l) {
  // wave-uniform LDS base; HW scatters lane i -> base + i*16 bytes [m104]
  __builtin_amdgcn_global_load_lds(
      (const __attribute__((address_space(1))) unsigned int*)g,
      (__attribute__((address_space(3))) unsigned int*)l, 16, 0, 0);
}

// ------------------------------- cvt pass ----------------------------------
struct CvtJobs {
  const float* src[7];
  _Float16* dst[7];
  int n4[7];
};

__global__ __launch_bounds__(256) void cvt_kernel(CvtJobs j) {
  const int stride = gridDim.x * blockDim.x;
  const int t0 = blockIdx.x * blockDim.x + threadIdx.x;
#pragma unroll
  for (int k = 0; k < 7; ++k) {
    const float4* __restrict__ s = (const float4*)j.src[k];
    h4* __restrict__ d = (h4*)j.dst[k];
    const int n = j.n4[k];
    for (int i = t0; i < n; i += stride) {
      const float4 f = s[i];
      h4 h;
      h[0] = (_Float16)f.x; h[1] = (_Float16)f.y;
      h[2] = (_Float16)f.z; h[3] = (_Float16)f.w;
      d[i] = h;
    }
  }
}

// ------------------------------- QKV GEMM ----------------------------------
struct QkvArgs {
  const _Float16* X[3];
  const _Float16* W[3];
  const float* bias[3];
  _Float16* out[3];
};

// C = X @ W^T + bias. 128x128 tile, BK=64, 4 waves 2x2, m97 staging,
// DIRECT-store epilogue (no LDS round-trip, no extra barriers).
// z=0: Q*0.125*log2e -> [B,H,S,64]; z=1: K -> [B,H,S,64]; z=2: V^T -> [B,H,64,S]
__global__ __launch_bounds__(256) void gemm_qkv(QkvArgs args) {
  const int z = blockIdx.z;
  const _Float16* __restrict__ X = args.X[z];
  const _Float16* __restrict__ W = args.W[z];
  const float* __restrict__ bias = args.bias[z];
  _Float16* __restrict__ out = args.out[z];

  __shared__ _Float16 As[128 * 64];
  __shared__ _Float16 Bs[128 * 64];

  const int t = threadIdx.x;
  const int lane = t & 63, wv = t >> 6;
  const int l15 = lane & 15, quad = lane >> 4;
  const int wm = (wv >> 1) * 64, wn = (wv & 1) * 64;
  const int n0 = blockIdx.x * 128, m0 = blockIdx.y * 128;

  f4 acc[4][4];
#pragma unroll
  for (int i = 0; i < 4; ++i)
#pragma unroll
    for (int j = 0; j < 4; ++j) {
      f4 zz = {0.f, 0.f, 0.f, 0.f};
      acc[i][j] = zz;
    }

  const int srow = lane >> 3, scol = (lane & 7) * 8;

  for (int k0 = 0; k0 < Kn; k0 += 64) {
    __syncthreads();
#pragma unroll
    for (int u = 0; u < 4; ++u) {
      const int s = wv * 4 + u;
      const int row = s * 8 + srow;
      gload_lds16(X + (size_t)(m0 + row) * Kn + k0 + scol, As + s * 512);
      gload_lds16(W + (size_t)(n0 + row) * Kn + k0 + scol, Bs + s * 512);
    }
    __syncthreads();
#pragma unroll
    for (int kk = 0; kk < 64; kk += 32) {
      h8 af[4], bfr[4];
#pragma unroll
      for (int i = 0; i < 4; ++i)
        af[i] = *(const h8*)&As[(wm + i * 16 + l15) * 64 + kk + quad * 8];
#pragma unroll
      for (int j = 0; j < 4; ++j)
        bfr[j] = *(const h8*)&Bs[(wn + j * 16 + l15) * 64 + kk + quad * 8];
#pragma unroll
      for (int i = 0; i < 4; ++i)
#pragma unroll
        for (int j = 0; j < 4; ++j)
          acc[i][j] = MFMA16(af[i], bfr[j], acc[i][j]);
    }
  }

  // ---- direct-store epilogue; C/D layout col=l15, row=quad*4+r [m89/m91] ----
  const float osc = (z == 0) ? (0.125f * LOG2E) : 1.0f;
  if (z != 2) {
#pragma unroll
    for (int j = 0; j < 4; ++j) {
      const int n = n0 + wn + j * 16 + l15;
      const float bvs = bias[n] * osc;
      const int hh = n >> 6, hd = n & 63;
#pragma unroll
      for (int i = 0; i < 4; ++i) {
        const int mb = m0 + wm + i * 16 + quad * 4;
        const int bb = mb >> 11;
#pragma unroll
        for (int r = 0; r < 4; ++r) {
          const int ss = (mb + r) & (Sn - 1);
          out[(((size_t)(bb * Hn + hh)) * Sn + ss) * HDn + hd] =
              (_Float16)(acc[i][j][r] * osc + bvs);
        }
      }
    }
  } else {
#pragma unroll
    for (int j = 0; j < 4; ++j) {
      const int n = n0 + wn + j * 16 + l15;
      const float bv = bias[n];
      const int hh = n >> 6, hd = n & 63;
#pragma unroll
      for (int i = 0; i < 4; ++i) {
        const int mb = m0 + wm + i * 16 + quad * 4;
        const int bb = mb >> 11, ss = mb & (Sn - 1);
        h4 hv;
#pragma unroll
        for (int r = 0; r < 4; ++r) hv[r] = (_Float16)(acc[i][j][r] + bv);
        *(h4*)(out + (((size_t)(bb * Hn + hh)) * HDn + hd) * Sn + ss) = hv;
      }
    }
  }
}

// ------------------------------- O GEMM ------------------------------------
__global__ __launch_bounds__(256) void gemm_o(const _Float16* __restrict__ X,
                                              const _Float16* __restrict__ W,
                                              const float* __restrict__ bias,
                                              float* __restrict__ out) {
  __shared__ _Float16 As[128 * 64];
  __shared__ _Float16 Bs[128 * 64];

  const int t = threadIdx.x;
  const int lane = t & 63, wv = t >> 6;
  const int l15 = lane & 15, quad = lane >> 4;
  const int wm = (wv >> 1) * 64, wn = (wv & 1) * 64;
  const int n0 = blockIdx.x * 128, m0 = blockIdx.y * 128;

  f4 acc[4][4];
#pragma unroll
  for (int i = 0; i < 4; ++i)
#pragma unroll
    for (int j = 0; j < 4; ++j) {
      f4 zz = {0.f, 0.f, 0.f, 0.f};
      acc[i][j] = zz;
    }

  const int srow = lane >> 3, scol = (lane & 7) * 8;

  for (int k0 = 0; k0 < Kn; k0 += 64) {
    __syncthreads();
#pragma unroll
    for (int u = 0; u < 4; ++u) {
      const int s = wv * 4 + u;
      const int row = s * 8 + srow;
      gload_lds16(X + (size_t)(m0 + row) * Kn + k0 + scol, As + s * 512);
      gload_lds16(W + (size_t)(n0 + row) * Kn + k0 + scol, Bs + s * 512);
    }
    __syncthreads();
#pragma unroll
    for (int kk = 0; kk < 64; kk += 32) {
      h8 af[4], bfr[4];
#pragma unroll
      for (int i = 0; i < 4; ++i)
        af[i] = *(const h8*)&As[(wm + i * 16 + l15) * 64 + kk + quad * 8];
#pragma unroll
      for (int j = 0; j < 4; ++j)
        bfr[j] = *(const h8*)&Bs[(wn + j * 16 + l15) * 64 + kk + quad * 8];
#pragma unroll
      for (int i = 0; i < 4; ++i)
#pragma unroll
        for (int j = 0; j < 4; ++j)
          acc[i][j] = MFMA16(af[i], bfr[j], acc[i][j]);
    }
  }

#pragma unroll
  for (int j = 0; j < 4; ++j) {
    const int n = n0 + wn + j * 16 + l15;
    const float bv = bias[n];
#pragma unroll
    for (int i = 0; i < 4; ++i) {
      const int mb = m0 + wm + i * 16 + quad * 4;
#pragma unroll
      for (int r = 0; r < 4; ++r)
        out[(size_t)(mb + r) * Nn + n] = acc[i][j][r] + bv;
    }
  }
}

// ------------------------------ attention ----------------------------------
// Transposed scores S^T = K Q^T (C col = l15 = q). Block = 4 waves x 16 q.
// Double-buffered K/V tiles via global_load_lds; ONE barrier per 64-key tile.
__global__ __launch_bounds__(256) void attn_kernel(
    const _Float16* __restrict__ Qh,   // [B,H,S,64], pre-scaled by 0.125*log2e
    const _Float16* __restrict__ Kh,   // [B,H,S,64]
    const _Float16* __restrict__ Vt,   // [B,H,64,S]
    const float* __restrict__ mask,    // [B,S,S] fp32
    _Float16* __restrict__ out) {      // [B,S,1024] fp16
  __shared__ _Float16 Kl[2][64 * 64];  // unpadded (global_load_lds layout)
  __shared__ _Float16 Vl[2][64 * 64];
  __shared__ _Float16 Pl[4 * 16 * LDP];

  const int t = threadIdx.x;
  const int w = t >> 6, lane = t & 63;
  const int l15 = lane & 15, quad = lane >> 4;

  const int bh = blockIdx.y;
  const int b = bh >> 4, h = bh & 15;
  const size_t headoff = (size_t)bh * Sn * HDn;
  const _Float16* Qp = Qh + headoff;
  const _Float16* Kp = Kh + headoff;
  const _Float16* Vp = Vt + headoff;

  const int qb = blockIdx.x * 64;
  const int q0 = qb + w * 16;
  // Q as B-operand: n = l15 -> q, k = quad*8+j -> d
  const h8 qf0 = *(const h8*)(Qp + (size_t)(q0 + l15) * HDn + quad * 8);
  const h8 qf1 = *(const h8*)(Qp + (size_t)(q0 + l15) * HDn + 32 + quad * 8);

  const float* mrow = mask + ((size_t)b * Sn + q0 + l15) * Sn;  // lane's q row

  float m_run = -INFINITY, l_run = 0.f;
  f4 o_acc[4];
#pragma unroll
  for (int nt = 0; nt < 4; ++nt) {
    f4 zz = {0.f, 0.f, 0.f, 0.f};
    o_acc[nt] = zz;
  }

  _Float16* Pw = &Pl[(w * 16) * LDP];

  // staging: wave w covers slabs {2w, 2w+1}; slab = 8 rows of 64 halfs (1 KB)
  const int r8 = lane >> 3, c8 = (lane & 7) * 8;
  auto stage = [&](int kt, int bufi) {
#pragma unroll
    for (int u = 0; u < 2; ++u) {
      const int s = w * 2 + u;  // wave-uniform slab id
      gload_lds16(Kp + (size_t)(kt * 64 + s * 8 + r8) * HDn + c8,
                  &Kl[bufi][s * 512]);
      gload_lds16(Vp + (size_t)(s * 8 + r8) * Sn + kt * 64 + c8,
                  &Vl[bufi][s * 512]);
    }
  };

  stage(0, 0);

  for (int kt = 0; kt < Sn / 64; ++kt) {
    const int cur = kt & 1;
    __syncthreads();  // drains own prefetch (vmcnt) + all waves done with prev
    if (kt + 1 < Sn / 64) stage(kt + 1, cur ^ 1);  // async during compute
    const _Float16* Kc = Kl[cur];
    const _Float16* Vc = Vl[cur];

    // ---- S^T = K Q^T: rows = keys (quad*4+r), cols = q (l15) ----
    f4 s[4];
#pragma unroll
    for (int ks = 0; ks < 4; ++ks) {
      const h8 kf0 = *(const h8*)&Kc[(ks * 16 + l15) * 64 + quad * 8];
      const h8 kf1 = *(const h8*)&Kc[(ks * 16 + l15) * 64 + 32 + quad * 8];
      f4 a = {0.f, 0.f, 0.f, 0.f};
      a = MFMA16(kf0, qf0, a);
      a = MFMA16(kf1, qf1, a);
      const float4 mv = *(const float4*)(mrow + kt * 64 + ks * 16 + quad * 4);
#pragma unroll
      for (int r = 0; r < 4; ++r)
        s[ks][r] = fmaf(((const float*)&mv)[r], LOG2E, a[r]);  // log2 domain
    }

    // ---- per-lane scalar online softmax (exp2 domain) ----
    float mx = s[0][0];
#pragma unroll
    for (int ks = 0; ks < 4; ++ks)
#pragma unroll
      for (int r = 0; r < 4; ++r) mx = fmaxf(mx, s[ks][r]);
    mx = fmaxf(mx, __shfl_xor(mx, 16));
    mx = fmaxf(mx, __shfl_xor(mx, 32));
    const float nm = fmaxf(m_run, mx);
    const float alpha = EXP2F(m_run - nm);
    m_run = nm;
    float sm = 0.f;
#pragma unroll
    for (int ks = 0; ks < 4; ++ks)
#pragma unroll
      for (int r = 0; r < 4; ++r) {
        s[ks][r] = EXP2F(s[ks][r] - nm);
        sm += s[ks][r];
      }
    sm += __shfl_xor(sm, 16);
    sm += __shfl_xor(sm, 32);
    l_run = l_run * alpha + sm;
#pragma unroll
    for (int nt = 0; nt < 4; ++nt)
#pragma unroll
      for (int r = 0; r < 4; ++r) o_acc[nt][r] *= alpha;

    // ---- P^T packed write: Pw[q=l15][key], b64 stores (wave-private) ----
#pragma unroll
    for (int ks = 0; ks < 4; ++ks) {
      h4 pv;
#pragma unroll
      for (int r = 0; r < 4; ++r) pv[r] = (_Float16)s[ks][r];
      *(h4*)&Pw[l15 * LDP + ks * 16 + quad * 4] = pv;
    }
    // in-wave DS ordering -> no barrier (validated R4)

    // ---- O^T += V^T P^T ----
#pragma unroll
    for (int kk = 0; kk < 64; kk += 32) {
      const h8 pf = *(const h8*)&Pw[l15 * LDP + kk + quad * 8];
#pragma unroll
      for (int nt = 0; nt < 4; ++nt) {
        const h8 vf = *(const h8*)&Vc[(nt * 16 + l15) * 64 + kk + quad * 8];
        o_acc[nt] = MFMA16(vf, pf, o_acc[nt]);
      }
    }
  }

  // ---- epilogue: O^T -> wave-private LDS transpose -> coalesced stores ----
  const float rl = 1.0f / l_run;
#pragma unroll
  for (int nt = 0; nt < 4; ++nt) {
    h4 ov;
#pragma unroll
    for (int r = 0; r < 4; ++r) ov[r] = (_Float16)(o_acc[nt][r] * rl);
    *(h4*)&Pw[l15 * LDP + nt * 16 + quad * 4] = ov;  // Ob[q_local][d]
  }
  const int qr = lane >> 2;            // 0..15
  const int seg = (lane & 3) * 16;     // 0,16,32,48
  const int qg = q0 + qr;
  _Float16* dst = out + ((size_t)b * Sn + qg) * Dn + h * 64 + seg;
  *(uint4*)dst = *(const uint4*)&Pw[qr * LDP + seg];
  *(uint4*)(dst + 8) = *(const uint4*)&Pw[qr * LDP + seg + 8];
}

// ------------------------------ launch -------------------------------------
extern "C" void kernel_launch(void* const* d_in, const int* in_sizes, int n_in,
                              void* d_out, int out_size, void* d_ws, size_t ws_size,
                              hipStream_t stream) {
  const float* q = (const float*)d_in[0];
  const float* k = (const float*)d_in[1];
  const float* v = (const float*)d_in[2];
  const float* mask = (const float*)d_in[3];
  const float* WQ = (const float*)d_in[4];
  const float* bQ = (const float*)d_in[5];
  const float* WK = (const float*)d_in[6];
  const float* bK = (const float*)d_in[7];
  const float* WV = (const float*)d_in[8];
  const float* bV = (const float*)d_in[9];
  const float* WO = (const float*)d_in[10];
  const float* bO = (const float*)d_in[11];

  _Float16* ws = (_Float16*)d_ws;
  const size_t MD = (size_t)Mn * Dn;   // 4.19M elems
  const size_t DD = (size_t)Dn * Dn;   // 1.05M
  _Float16* qh  = ws;
  _Float16* kh  = ws + MD;
  _Float16* vh  = ws + 2 * MD;
  _Float16* WQh = ws + 3 * MD;
  _Float16* WKh = WQh + DD;
  _Float16* WVh = WKh + DD;
  _Float16* WOh = WVh + DD;
  _Float16* Qh  = ws + 3 * MD + 4 * DD;
  _Float16* Kh  = Qh + MD;
  _Float16* Vt  = Kh + MD;
  _Float16* AO  = qh;  // qh dead after QKV gemm

  CvtJobs cj;
  cj.src[0] = q;  cj.dst[0] = qh;  cj.n4[0] = (int)(MD / 4);
  cj.src[1] = k;  cj.dst[1] = kh;  cj.n4[1] = (int)(MD / 4);
  cj.src[2] = v;  cj.dst[2] = vh;  cj.n4[2] = (int)(MD / 4);
  cj.src[3] = WQ; cj.dst[3] = WQh; cj.n4[3] = (int)(DD / 4);
  cj.src[4] = WK; cj.dst[4] = WKh; cj.n4[4] = (int)(DD / 4);
  cj.src[5] = WV; cj.dst[5] = WVh; cj.n4[5] = (int)(DD / 4);
  cj.src[6] = WO; cj.dst[6] = WOh; cj.n4[6] = (int)(DD / 4);
  cvt_kernel<<<1024, 256, 0, stream>>>(cj);

  QkvArgs ga;
  ga.X[0] = qh; ga.W[0] = WQh; ga.bias[0] = bQ; ga.out[0] = Qh;
  ga.X[1] = kh; ga.W[1] = WKh; ga.bias[1] = bK; ga.out[1] = Kh;
  ga.X[2] = vh; ga.W[2] = WVh; ga.bias[2] = bV; ga.out[2] = Vt;
  gemm_qkv<<<dim3(Nn / 128, Mn / 128, 3), 256, 0, stream>>>(ga);

  attn_kernel<<<dim3(Sn / 64, Bn * Hn), 256, 0, stream>>>(Qh, Kh, Vt, mask, AO);

  gemm_o<<<dim3(Nn / 128, Mn / 128), 256, 0, stream>>>(AO, WOh, bO, (float*)d_out);
}

// Round 7
// 302.177 us; speedup vs baseline: 1.2258x; 1.2258x over previous
//
#include <hip/hip_runtime.h>
#include <math.h>

// ---------------------------------------------------------------------------
// MultiheadAttention B=2,S=2048,D=1024,H=16,HD=64. I/O fp32; internal fp16 MFMA.
//   0) cvt: q,k,v,WQ..WO fp32 -> fp16 (once)
//   1) gemm_qkv (m97 staging, direct-store epilogue):
//      Q fp16 [B,H,S,64] pre-scaled by 0.125*log2e, K fp16 [B,H,S,64],
//      V fp16 transposed [B,H,64,S]
//   2) attn: transposed scores S^T = K Q^T, exp2 softmax, PADDED LDS (R4
//      structure), IN-BLOCK SPLIT-K x2 (512 thr: waves 0-3 keys 0..1023,
//      waves 4-7 keys 1024..2047), flash combine via LDS -> AO fp16
//   3) gemm_o: AO @ WO^T + b -> d_out fp32
// ---------------------------------------------------------------------------

typedef _Float16 h8 __attribute__((ext_vector_type(8)));
typedef _Float16 h4 __attribute__((ext_vector_type(4)));
typedef float f4 __attribute__((ext_vector_type(4)));

#define MFMA16(a, b, c) __builtin_amdgcn_mfma_f32_16x16x32_f16((a), (b), (c), 0, 0, 0)
#define EXP2F(x) __builtin_amdgcn_exp2f(x)   // v_exp_f32 = 2^x

static constexpr int Bn = 2, Sn = 2048, Dn = 1024, Hn = 16, HDn = 64;
static constexpr int Mn = Bn * Sn;   // 4096
static constexpr int Kn = Dn;        // 1024
static constexpr int Nn = Dn;        // 1024
static constexpr int LDP = 72;       // attn LDS stride (64 + 8 pad) — conflict-free [R4: 11.6M vs R6 unpadded 28.4M]
static constexpr float LOG2E = 1.4426950408889634f;

__device__ __forceinline__ void gload_lds16(const _Float16* g, _Float16* l) {
  // wave-uniform LDS base; HW scatters lane i -> base + i*16 bytes [m104]
  __builtin_amdgcn_global_load_lds(
      (const __attribute__((address_space(1))) unsigned int*)g,
      (__attribute__((address_space(3))) unsigned int*)l, 16, 0, 0);
}

// ------------------------------- cvt pass ----------------------------------
struct CvtJobs {
  const float* src[7];
  _Float16* dst[7];
  int n4[7];
};

__global__ __launch_bounds__(256) void cvt_kernel(CvtJobs j) {
  const int stride = gridDim.x * blockDim.x;
  const int t0 = blockIdx.x * blockDim.x + threadIdx.x;
#pragma unroll
  for (int k = 0; k < 7; ++k) {
    const float4* __restrict__ s = (const float4*)j.src[k];
    h4* __restrict__ d = (h4*)j.dst[k];
    const int n = j.n4[k];
    for (int i = t0; i < n; i += stride) {
      const float4 f = s[i];
      h4 h;
      h[0] = (_Float16)f.x; h[1] = (_Float16)f.y;
      h[2] = (_Float16)f.z; h[3] = (_Float16)f.w;
      d[i] = h;
    }
  }
}

// ------------------------------- QKV GEMM ----------------------------------
struct QkvArgs {
  const _Float16* X[3];
  const _Float16* W[3];
  const float* bias[3];
  _Float16* out[3];
};

// C = X @ W^T + bias. 128x128 tile, BK=64, 4 waves 2x2, m97 staging,
// direct-store epilogue.
// z=0: Q*0.125*log2e -> [B,H,S,64]; z=1: K -> [B,H,S,64]; z=2: V^T -> [B,H,64,S]
__global__ __launch_bounds__(256) void gemm_qkv(QkvArgs args) {
  const int z = blockIdx.z;
  const _Float16* __restrict__ X = args.X[z];
  const _Float16* __restrict__ W = args.W[z];
  const float* __restrict__ bias = args.bias[z];
  _Float16* __restrict__ out = args.out[z];

  __shared__ _Float16 As[128 * 64];
  __shared__ _Float16 Bs[128 * 64];

  const int t = threadIdx.x;
  const int lane = t & 63, wv = t >> 6;
  const int l15 = lane & 15, quad = lane >> 4;
  const int wm = (wv >> 1) * 64, wn = (wv & 1) * 64;
  const int n0 = blockIdx.x * 128, m0 = blockIdx.y * 128;

  f4 acc[4][4];
#pragma unroll
  for (int i = 0; i < 4; ++i)
#pragma unroll
    for (int j = 0; j < 4; ++j) {
      f4 zz = {0.f, 0.f, 0.f, 0.f};
      acc[i][j] = zz;
    }

  const int srow = lane >> 3, scol = (lane & 7) * 8;

  for (int k0 = 0; k0 < Kn; k0 += 64) {
    __syncthreads();
#pragma unroll
    for (int u = 0; u < 4; ++u) {
      const int s = wv * 4 + u;
      const int row = s * 8 + srow;
      gload_lds16(X + (size_t)(m0 + row) * Kn + k0 + scol, As + s * 512);
      gload_lds16(W + (size_t)(n0 + row) * Kn + k0 + scol, Bs + s * 512);
    }
    __syncthreads();
#pragma unroll
    for (int kk = 0; kk < 64; kk += 32) {
      h8 af[4], bfr[4];
#pragma unroll
      for (int i = 0; i < 4; ++i)
        af[i] = *(const h8*)&As[(wm + i * 16 + l15) * 64 + kk + quad * 8];
#pragma unroll
      for (int j = 0; j < 4; ++j)
        bfr[j] = *(const h8*)&Bs[(wn + j * 16 + l15) * 64 + kk + quad * 8];
#pragma unroll
      for (int i = 0; i < 4; ++i)
#pragma unroll
        for (int j = 0; j < 4; ++j)
          acc[i][j] = MFMA16(af[i], bfr[j], acc[i][j]);
    }
  }

  // ---- direct-store epilogue; C/D layout col=l15, row=quad*4+r [m89/m91] ----
  const float osc = (z == 0) ? (0.125f * LOG2E) : 1.0f;
  if (z != 2) {
#pragma unroll
    for (int j = 0; j < 4; ++j) {
      const int n = n0 + wn + j * 16 + l15;
      const float bvs = bias[n] * osc;
      const int hh = n >> 6, hd = n & 63;
#pragma unroll
      for (int i = 0; i < 4; ++i) {
        const int mb = m0 + wm + i * 16 + quad * 4;
        const int bb = mb >> 11;
#pragma unroll
        for (int r = 0; r < 4; ++r) {
          const int ss = (mb + r) & (Sn - 1);
          out[(((size_t)(bb * Hn + hh)) * Sn + ss) * HDn + hd] =
              (_Float16)(acc[i][j][r] * osc + bvs);
        }
      }
    }
  } else {
#pragma unroll
    for (int j = 0; j < 4; ++j) {
      const int n = n0 + wn + j * 16 + l15;
      const float bv = bias[n];
      const int hh = n >> 6, hd = n & 63;
#pragma unroll
      for (int i = 0; i < 4; ++i) {
        const int mb = m0 + wm + i * 16 + quad * 4;
        const int bb = mb >> 11, ss = mb & (Sn - 1);
        h4 hv;
#pragma unroll
        for (int r = 0; r < 4; ++r) hv[r] = (_Float16)(acc[i][j][r] + bv);
        *(h4*)(out + (((size_t)(bb * Hn + hh)) * HDn + hd) * Sn + ss) = hv;
      }
    }
  }
}

// ------------------------------- O GEMM ------------------------------------
__global__ __launch_bounds__(256) void gemm_o(const _Float16* __restrict__ X,
                                              const _Float16* __restrict__ W,
                                              const float* __restrict__ bias,
                                              float* __restrict__ out) {
  __shared__ _Float16 As[128 * 64];
  __shared__ _Float16 Bs[128 * 64];

  const int t = threadIdx.x;
  const int lane = t & 63, wv = t >> 6;
  const int l15 = lane & 15, quad = lane >> 4;
  const int wm = (wv >> 1) * 64, wn = (wv & 1) * 64;
  const int n0 = blockIdx.x * 128, m0 = blockIdx.y * 128;

  f4 acc[4][4];
#pragma unroll
  for (int i = 0; i < 4; ++i)
#pragma unroll
    for (int j = 0; j < 4; ++j) {
      f4 zz = {0.f, 0.f, 0.f, 0.f};
      acc[i][j] = zz;
    }

  const int srow = lane >> 3, scol = (lane & 7) * 8;

  for (int k0 = 0; k0 < Kn; k0 += 64) {
    __syncthreads();
#pragma unroll
    for (int u = 0; u < 4; ++u) {
      const int s = wv * 4 + u;
      const int row = s * 8 + srow;
      gload_lds16(X + (size_t)(m0 + row) * Kn + k0 + scol, As + s * 512);
      gload_lds16(W + (size_t)(n0 + row) * Kn + k0 + scol, Bs + s * 512);
    }
    __syncthreads();
#pragma unroll
    for (int kk = 0; kk < 64; kk += 32) {
      h8 af[4], bfr[4];
#pragma unroll
      for (int i = 0; i < 4; ++i)
        af[i] = *(const h8*)&As[(wm + i * 16 + l15) * 64 + kk + quad * 8];
#pragma unroll
      for (int j = 0; j < 4; ++j)
        bfr[j] = *(const h8*)&Bs[(wn + j * 16 + l15) * 64 + kk + quad * 8];
#pragma unroll
      for (int i = 0; i < 4; ++i)
#pragma unroll
        for (int j = 0; j < 4; ++j)
          acc[i][j] = MFMA16(af[i], bfr[j], acc[i][j]);
    }
  }

#pragma unroll
  for (int j = 0; j < 4; ++j) {
    const int n = n0 + wn + j * 16 + l15;
    const float bv = bias[n];
#pragma unroll
    for (int i = 0; i < 4; ++i) {
      const int mb = m0 + wm + i * 16 + quad * 4;
#pragma unroll
      for (int r = 0; r < 4; ++r)
        out[(size_t)(mb + r) * Nn + n] = acc[i][j][r] + bv;
    }
  }
}

// ------------------------------ attention ----------------------------------
// Transposed scores S^T = K Q^T (C col = l15 = q). 512 threads = 8 waves.
// Split-K x2: group g = wave>>2 handles keys [g*1024, g*1024+1024).
// Wave pair (w, w+4) owns the same 16 q rows; flash-combine via LDS at end.
__global__ __launch_bounds__(512) void attn_kernel(
    const _Float16* __restrict__ Qh,   // [B,H,S,64], pre-scaled by 0.125*log2e
    const _Float16* __restrict__ Kh,   // [B,H,S,64]
    const _Float16* __restrict__ Vt,   // [B,H,64,S]
    const float* __restrict__ mask,    // [B,S,S] fp32
    _Float16* __restrict__ out) {      // [B,S,1024] fp16
  __shared__ _Float16 smem[4 * 64 * LDP];  // K0,K1,V0,V1 (padded); combine area reuses this
  __shared__ _Float16 Pl[8 * 16 * LDP];

  const int t = threadIdx.x;
  const int w = t >> 6, lane = t & 63;
  const int l15 = lane & 15, quad = lane >> 4;
  const int g = w >> 2;    // key-half group
  const int wq = w & 3;    // q-subtile id (shared by pair w, w+4)

  const int bh = blockIdx.y;
  const int b = bh >> 4, h = bh & 15;
  const size_t headoff = (size_t)bh * Sn * HDn;
  const _Float16* Qp = Qh + headoff;
  const _Float16* Kp = Kh + headoff;
  const _Float16* Vp = Vt + headoff;

  const int qb = blockIdx.x * 64;
  const int q0 = qb + wq * 16;
  // Q as B-operand: n = l15 -> q, k = quad*8+j -> d
  const h8 qf0 = *(const h8*)(Qp + (size_t)(q0 + l15) * HDn + quad * 8);
  const h8 qf1 = *(const h8*)(Qp + (size_t)(q0 + l15) * HDn + 32 + quad * 8);

  const int kbase = g * (Sn / 2);
  const float* mrow = mask + ((size_t)b * Sn + q0 + l15) * Sn + kbase;

  float m_run = -INFINITY, l_part = 0.f;   // l kept lane-partial (quad-reduced once at end)
  f4 o_acc[4];
#pragma unroll
  for (int nt = 0; nt < 4; ++nt) {
    f4 zz = {0.f, 0.f, 0.f, 0.f};
    o_acc[nt] = zz;
  }

  _Float16* Kg = smem + g * (64 * LDP);
  _Float16* Vg = smem + (2 + g) * (64 * LDP);
  _Float16* Pw = &Pl[(w * 16) * LDP];

  const int tg = t & 255;  // staging index within group (4 waves = 256 threads)

  for (int kt = 0; kt < (Sn / 2) / 64; ++kt) {
    __syncthreads();  // prior tile's LDS reads complete (both groups in lockstep)
#pragma unroll
    for (int u = 0; u < 2; ++u) {
      const int c = tg + u * 256;  // 512 chunks of 8 halfs per matrix per group
      const int row = c >> 3, c8 = (c & 7) * 8;
      *(uint4*)&Kg[row * LDP + c8] =
          *(const uint4*)(Kp + (size_t)(kbase + kt * 64 + row) * HDn + c8);
      *(uint4*)&Vg[row * LDP + c8] =
          *(const uint4*)(Vp + (size_t)row * Sn + kbase + kt * 64 + c8);
    }
    __syncthreads();

    // ---- S^T = K Q^T: rows = keys (quad*4+r), cols = q (l15) ----
    f4 s[4];
#pragma unroll
    for (int ks = 0; ks < 4; ++ks) {
      const h8 kf0 = *(const h8*)&Kg[(ks * 16 + l15) * LDP + quad * 8];
      const h8 kf1 = *(const h8*)&Kg[(ks * 16 + l15) * LDP + 32 + quad * 8];
      f4 a = {0.f, 0.f, 0.f, 0.f};
      a = MFMA16(kf0, qf0, a);
      a = MFMA16(kf1, qf1, a);
      const float4 mv = *(const float4*)(mrow + kt * 64 + ks * 16 + quad * 4);
#pragma unroll
      for (int r = 0; r < 4; ++r)
        s[ks][r] = fmaf(((const float*)&mv)[r], LOG2E, a[r]);  // log2 domain
    }

    // ---- per-lane online softmax (exp2 domain); l stays lane-partial ----
    float mx = s[0][0];
#pragma unroll
    for (int ks = 0; ks < 4; ++ks)
#pragma unroll
      for (int r = 0; r < 4; ++r) mx = fmaxf(mx, s[ks][r]);
    mx = fmaxf(mx, __shfl_xor(mx, 16));
    mx = fmaxf(mx, __shfl_xor(mx, 32));
    const float nm = fmaxf(m_run, mx);
    const float alpha = EXP2F(m_run - nm);
    m_run = nm;
    float sm = 0.f;
#pragma unroll
    for (int ks = 0; ks < 4; ++ks)
#pragma unroll
      for (int r = 0; r < 4; ++r) {
        s[ks][r] = EXP2F(s[ks][r] - nm);
        sm += s[ks][r];
      }
    l_part = l_part * alpha + sm;
#pragma unroll
    for (int nt = 0; nt < 4; ++nt)
#pragma unroll
      for (int r = 0; r < 4; ++r) o_acc[nt][r] *= alpha;

    // ---- P^T packed write: Pw[q=l15][key], b64 stores (wave-private) ----
#pragma unroll
    for (int ks = 0; ks < 4; ++ks) {
      h4 pv;
#pragma unroll
      for (int r = 0; r < 4; ++r) pv[r] = (_Float16)s[ks][r];
      *(h4*)&Pw[l15 * LDP + ks * 16 + quad * 4] = pv;
    }
    // in-wave DS ordering -> no barrier (validated R4)

    // ---- U^T += V^T P^T (unnormalized) ----
#pragma unroll
    for (int kk = 0; kk < 64; kk += 32) {
      const h8 pf = *(const h8*)&Pw[l15 * LDP + kk + quad * 8];
#pragma unroll
      for (int nt = 0; nt < 4; ++nt) {
        const h8 vf = *(const h8*)&Vg[(nt * 16 + l15) * LDP + kk + quad * 8];
        o_acc[nt] = MFMA16(vf, pf, o_acc[nt]);
      }
    }
  }

  // ---- quad-reduce l (deferred from the loop) ----
  l_part += __shfl_xor(l_part, 16);
  l_part += __shfl_xor(l_part, 32);

  // ---- flash combine across the two key halves (pair w <-> w+4) ----
  __syncthreads();  // all main-loop smem reads done; reuse smem as fp32 area
  float* Uex = (float*)smem;            // [pair][q=16][stride 72] fp32
  float* mex = Uex + 4 * 16 * LDP;      // 4*16*72 = 4608 floats
  float* lex = mex + 64;
  if (g == 1) {
#pragma unroll
    for (int nt = 0; nt < 4; ++nt)
      *(f4*)&Uex[wq * 16 * LDP + l15 * LDP + nt * 16 + quad * 4] = o_acc[nt];
    if (quad == 0) {
      mex[wq * 16 + l15] = m_run;
      lex[wq * 16 + l15] = l_part;
    }
  }
  __syncthreads();
  if (g == 0) {
    const float m1 = mex[wq * 16 + l15];
    const float l1 = lex[wq * 16 + l15];
    const float mm = fmaxf(m_run, m1);
    const float f0 = EXP2F(m_run - mm);
    const float f1 = EXP2F(m1 - mm);
    const float rl = 1.0f / (f0 * l_part + f1 * l1);
#pragma unroll
    for (int nt = 0; nt < 4; ++nt) {
      const f4 Ur = *(const f4*)&Uex[wq * 16 * LDP + l15 * LDP + nt * 16 + quad * 4];
      h4 ov;
#pragma unroll
      for (int r = 0; r < 4; ++r)
        ov[r] = (_Float16)((o_acc[nt][r] * f0 + Ur[r] * f1) * rl);
      *(h4*)&Pw[l15 * LDP + nt * 16 + quad * 4] = ov;  // Ob[q_local][d]
    }
    // wave-private transpose -> coalesced stores
    const int qr = lane >> 2;            // 0..15
    const int seg = (lane & 3) * 16;     // 0,16,32,48
    _Float16* dst = out + ((size_t)b * Sn + q0 + qr) * Dn + h * 64 + seg;
    *(uint4*)dst = *(const uint4*)&Pw[qr * LDP + seg];
    *(uint4*)(dst + 8) = *(const uint4*)&Pw[qr * LDP + seg + 8];
  }
}

// ------------------------------ launch -------------------------------------
extern "C" void kernel_launch(void* const* d_in, const int* in_sizes, int n_in,
                              void* d_out, int out_size, void* d_ws, size_t ws_size,
                              hipStream_t stream) {
  const float* q = (const float*)d_in[0];
  const float* k = (const float*)d_in[1];
  const float* v = (const float*)d_in[2];
  const float* mask = (const float*)d_in[3];
  const float* WQ = (const float*)d_in[4];
  const float* bQ = (const float*)d_in[5];
  const float* WK = (const float*)d_in[6];
  const float* bK = (const float*)d_in[7];
  const float* WV = (const float*)d_in[8];
  const float* bV = (const float*)d_in[9];
  const float* WO = (const float*)d_in[10];
  const float* bO = (const float*)d_in[11];

  _Float16* ws = (_Float16*)d_ws;
  const size_t MD = (size_t)Mn * Dn;   // 4.19M elems
  const size_t DD = (size_t)Dn * Dn;   // 1.05M
  _Float16* qh  = ws;
  _Float16* kh  = ws + MD;
  _Float16* vh  = ws + 2 * MD;
  _Float16* WQh = ws + 3 * MD;
  _Float16* WKh = WQh + DD;
  _Float16* WVh = WKh + DD;
  _Float16* WOh = WVh + DD;
  _Float16* Qh  = ws + 3 * MD + 4 * DD;
  _Float16* Kh  = Qh + MD;
  _Float16* Vt  = Kh + MD;
  _Float16* AO  = qh;  // qh dead after QKV gemm

  CvtJobs cj;
  cj.src[0] = q;  cj.dst[0] = qh;  cj.n4[0] = (int)(MD / 4);
  cj.src[1] = k;  cj.dst[1] = kh;  cj.n4[1] = (int)(MD / 4);
  cj.src[2] = v;  cj.dst[2] = vh;  cj.n4[2] = (int)(MD / 4);
  cj.src[3] = WQ; cj.dst[3] = WQh; cj.n4[3] = (int)(DD / 4);
  cj.src[4] = WK; cj.dst[4] = WKh; cj.n4[4] = (int)(DD / 4);
  cj.src[5] = WV; cj.dst[5] = WVh; cj.n4[5] = (int)(DD / 4);
  cj.src[6] = WO; cj.dst[6] = WOh; cj.n4[6] = (int)(DD / 4);
  cvt_kernel<<<1024, 256, 0, stream>>>(cj);

  QkvArgs ga;
  ga.X[0] = qh; ga.W[0] = WQh; ga.bias[0] = bQ; ga.out[0] = Qh;
  ga.X[1] = kh; ga.W[1] = WKh; ga.bias[1] = bK; ga.out[1] = Kh;
  ga.X[2] = vh; ga.W[2] = WVh; ga.bias[2] = bV; ga.out[2] = Vt;
  gemm_qkv<<<dim3(Nn / 128, Mn / 128, 3), 256, 0, stream>>>(ga);

  attn_kernel<<<dim3(Sn / 64, Bn * Hn), 512, 0, stream>>>(Qh, Kh, Vt, mask, AO);

  gemm_o<<<dim3(Nn / 128, Mn / 128), 256, 0, stream>>>(AO, WOh, bO, (float*)d_out);
}

// Round 8
// 299.244 us; speedup vs baseline: 1.2378x; 1.0098x over previous
//
#include <hip/hip_runtime.h>
#include <math.h>

// ---------------------------------------------------------------------------
// MultiheadAttention B=2,S=2048,D=1024,H=16,HD=64. I/O fp32; internal fp16 MFMA.
//   0) cvt: q,k,v,WQ..WO fp32 -> fp16 (once)
//   1) gemm_qkv (m97 staging, direct-store epilogue):
//      Q fp16 [B,H,S,64] pre-scaled by 0.125*log2e, K fp16 [B,H,S,64],
//      V fp16 transposed [B,H,64,S]
//   2) attn: transposed scores S^T = K Q^T, exp2 softmax, padded LDS,
//      in-block split-K x2 (512 thr), REGISTER-PREFETCH double-buffered
//      K/V/mask staging (global latency hidden behind one full tile) -> AO
//   3) gemm_o: AO @ WO^T + b -> d_out fp32
// ---------------------------------------------------------------------------

typedef _Float16 h8 __attribute__((ext_vector_type(8)));
typedef _Float16 h4 __attribute__((ext_vector_type(4)));
typedef float f4 __attribute__((ext_vector_type(4)));

#define MFMA16(a, b, c) __builtin_amdgcn_mfma_f32_16x16x32_f16((a), (b), (c), 0, 0, 0)
#define EXP2F(x) __builtin_amdgcn_exp2f(x)   // v_exp_f32 = 2^x

static constexpr int Bn = 2, Sn = 2048, Dn = 1024, Hn = 16, HDn = 64;
static constexpr int Mn = Bn * Sn;   // 4096
static constexpr int Kn = Dn;        // 1024
static constexpr int Nn = Dn;        // 1024
static constexpr int LDP = 72;       // LDS stride (64+8 pad): 36 dwords ≡ 4 (mod 32) -> near-conflict-free b128
static constexpr float LOG2E = 1.4426950408889634f;

__device__ __forceinline__ void gload_lds16(const _Float16* g, _Float16* l) {
  // wave-uniform LDS base; HW scatters lane i -> base + i*16 bytes [m104]
  __builtin_amdgcn_global_load_lds(
      (const __attribute__((address_space(1))) unsigned int*)g,
      (__attribute__((address_space(3))) unsigned int*)l, 16, 0, 0);
}

// ------------------------------- cvt pass ----------------------------------
struct CvtJobs {
  const float* src[7];
  _Float16* dst[7];
  int n4[7];
};

__global__ __launch_bounds__(256) void cvt_kernel(CvtJobs j) {
  const int stride = gridDim.x * blockDim.x;
  const int t0 = blockIdx.x * blockDim.x + threadIdx.x;
#pragma unroll
  for (int k = 0; k < 7; ++k) {
    const float4* __restrict__ s = (const float4*)j.src[k];
    h4* __restrict__ d = (h4*)j.dst[k];
    const int n = j.n4[k];
    for (int i = t0; i < n; i += stride) {
      const float4 f = s[i];
      h4 h;
      h[0] = (_Float16)f.x; h[1] = (_Float16)f.y;
      h[2] = (_Float16)f.z; h[3] = (_Float16)f.w;
      d[i] = h;
    }
  }
}

// ------------------------------- QKV GEMM ----------------------------------
struct QkvArgs {
  const _Float16* X[3];
  const _Float16* W[3];
  const float* bias[3];
  _Float16* out[3];
};

// C = X @ W^T + bias. 128x128 tile, BK=64, 4 waves 2x2, m97 staging,
// direct-store epilogue.
// z=0: Q*0.125*log2e -> [B,H,S,64]; z=1: K -> [B,H,S,64]; z=2: V^T -> [B,H,64,S]
__global__ __launch_bounds__(256) void gemm_qkv(QkvArgs args) {
  const int z = blockIdx.z;
  const _Float16* __restrict__ X = args.X[z];
  const _Float16* __restrict__ W = args.W[z];
  const float* __restrict__ bias = args.bias[z];
  _Float16* __restrict__ out = args.out[z];

  __shared__ _Float16 As[128 * 64];
  __shared__ _Float16 Bs[128 * 64];

  const int t = threadIdx.x;
  const int lane = t & 63, wv = t >> 6;
  const int l15 = lane & 15, quad = lane >> 4;
  const int wm = (wv >> 1) * 64, wn = (wv & 1) * 64;
  const int n0 = blockIdx.x * 128, m0 = blockIdx.y * 128;

  f4 acc[4][4];
#pragma unroll
  for (int i = 0; i < 4; ++i)
#pragma unroll
    for (int j = 0; j < 4; ++j) {
      f4 zz = {0.f, 0.f, 0.f, 0.f};
      acc[i][j] = zz;
    }

  const int srow = lane >> 3, scol = (lane & 7) * 8;

  for (int k0 = 0; k0 < Kn; k0 += 64) {
    __syncthreads();
#pragma unroll
    for (int u = 0; u < 4; ++u) {
      const int s = wv * 4 + u;
      const int row = s * 8 + srow;
      gload_lds16(X + (size_t)(m0 + row) * Kn + k0 + scol, As + s * 512);
      gload_lds16(W + (size_t)(n0 + row) * Kn + k0 + scol, Bs + s * 512);
    }
    __syncthreads();
#pragma unroll
    for (int kk = 0; kk < 64; kk += 32) {
      h8 af[4], bfr[4];
#pragma unroll
      for (int i = 0; i < 4; ++i)
        af[i] = *(const h8*)&As[(wm + i * 16 + l15) * 64 + kk + quad * 8];
#pragma unroll
      for (int j = 0; j < 4; ++j)
        bfr[j] = *(const h8*)&Bs[(wn + j * 16 + l15) * 64 + kk + quad * 8];
#pragma unroll
      for (int i = 0; i < 4; ++i)
#pragma unroll
        for (int j = 0; j < 4; ++j)
          acc[i][j] = MFMA16(af[i], bfr[j], acc[i][j]);
    }
  }

  // ---- direct-store epilogue; C/D layout col=l15, row=quad*4+r [m89/m91] ----
  const float osc = (z == 0) ? (0.125f * LOG2E) : 1.0f;
  if (z != 2) {
#pragma unroll
    for (int j = 0; j < 4; ++j) {
      const int n = n0 + wn + j * 16 + l15;
      const float bvs = bias[n] * osc;
      const int hh = n >> 6, hd = n & 63;
#pragma unroll
      for (int i = 0; i < 4; ++i) {
        const int mb = m0 + wm + i * 16 + quad * 4;
        const int bb = mb >> 11;
#pragma unroll
        for (int r = 0; r < 4; ++r) {
          const int ss = (mb + r) & (Sn - 1);
          out[(((size_t)(bb * Hn + hh)) * Sn + ss) * HDn + hd] =
              (_Float16)(acc[i][j][r] * osc + bvs);
        }
      }
    }
  } else {
#pragma unroll
    for (int j = 0; j < 4; ++j) {
      const int n = n0 + wn + j * 16 + l15;
      const float bv = bias[n];
      const int hh = n >> 6, hd = n & 63;
#pragma unroll
      for (int i = 0; i < 4; ++i) {
        const int mb = m0 + wm + i * 16 + quad * 4;
        const int bb = mb >> 11, ss = mb & (Sn - 1);
        h4 hv;
#pragma unroll
        for (int r = 0; r < 4; ++r) hv[r] = (_Float16)(acc[i][j][r] + bv);
        *(h4*)(out + (((size_t)(bb * Hn + hh)) * HDn + hd) * Sn + ss) = hv;
      }
    }
  }
}

// ------------------------------- O GEMM ------------------------------------
__global__ __launch_bounds__(256) void gemm_o(const _Float16* __restrict__ X,
                                              const _Float16* __restrict__ W,
                                              const float* __restrict__ bias,
                                              float* __restrict__ out) {
  __shared__ _Float16 As[128 * 64];
  __shared__ _Float16 Bs[128 * 64];

  const int t = threadIdx.x;
  const int lane = t & 63, wv = t >> 6;
  const int l15 = lane & 15, quad = lane >> 4;
  const int wm = (wv >> 1) * 64, wn = (wv & 1) * 64;
  const int n0 = blockIdx.x * 128, m0 = blockIdx.y * 128;

  f4 acc[4][4];
#pragma unroll
  for (int i = 0; i < 4; ++i)
#pragma unroll
    for (int j = 0; j < 4; ++j) {
      f4 zz = {0.f, 0.f, 0.f, 0.f};
      acc[i][j] = zz;
    }

  const int srow = lane >> 3, scol = (lane & 7) * 8;

  for (int k0 = 0; k0 < Kn; k0 += 64) {
    __syncthreads();
#pragma unroll
    for (int u = 0; u < 4; ++u) {
      const int s = wv * 4 + u;
      const int row = s * 8 + srow;
      gload_lds16(X + (size_t)(m0 + row) * Kn + k0 + scol, As + s * 512);
      gload_lds16(W + (size_t)(n0 + row) * Kn + k0 + scol, Bs + s * 512);
    }
    __syncthreads();
#pragma unroll
    for (int kk = 0; kk < 64; kk += 32) {
      h8 af[4], bfr[4];
#pragma unroll
      for (int i = 0; i < 4; ++i)
        af[i] = *(const h8*)&As[(wm + i * 16 + l15) * 64 + kk + quad * 8];
#pragma unroll
      for (int j = 0; j < 4; ++j)
        bfr[j] = *(const h8*)&Bs[(wn + j * 16 + l15) * 64 + kk + quad * 8];
#pragma unroll
      for (int i = 0; i < 4; ++i)
#pragma unroll
        for (int j = 0; j < 4; ++j)
          acc[i][j] = MFMA16(af[i], bfr[j], acc[i][j]);
    }
  }

#pragma unroll
  for (int j = 0; j < 4; ++j) {
    const int n = n0 + wn + j * 16 + l15;
    const float bv = bias[n];
#pragma unroll
    for (int i = 0; i < 4; ++i) {
      const int mb = m0 + wm + i * 16 + quad * 4;
#pragma unroll
      for (int r = 0; r < 4; ++r)
        out[(size_t)(mb + r) * Nn + n] = acc[i][j][r] + bv;
    }
  }
}

// ------------------------------ attention ----------------------------------
// Transposed scores S^T = K Q^T (C col = l15 = q). 512 threads = 8 waves.
// Split-K x2: group g = wave>>2 handles keys [g*1024, g*1024+1024).
// Register-prefetch double-buffer: tile kt+1's K/V/mask global loads are
// issued right after tile kt's LDS is ready, consumed one full tile later.
__global__ __launch_bounds__(512) void attn_kernel(
    const _Float16* __restrict__ Qh,   // [B,H,S,64], pre-scaled by 0.125*log2e
    const _Float16* __restrict__ Kh,   // [B,H,S,64]
    const _Float16* __restrict__ Vt,   // [B,H,64,S]
    const float* __restrict__ mask,    // [B,S,S] fp32
    _Float16* __restrict__ out) {      // [B,S,1024] fp16
  __shared__ _Float16 smem[4 * 64 * LDP];  // K0,K1,V0,V1 (padded); combine reuses
  __shared__ _Float16 Pl[8 * 16 * LDP];

  const int t = threadIdx.x;
  const int w = t >> 6, lane = t & 63;
  const int l15 = lane & 15, quad = lane >> 4;
  const int g = w >> 2;    // key-half group
  const int wq = w & 3;    // q-subtile id (shared by pair w, w+4)

  const int bh = blockIdx.y;
  const int b = bh >> 4, h = bh & 15;
  const size_t headoff = (size_t)bh * Sn * HDn;
  const _Float16* Qp = Qh + headoff;
  const _Float16* Kp = Kh + headoff;
  const _Float16* Vp = Vt + headoff;

  const int qb = blockIdx.x * 64;
  const int q0 = qb + wq * 16;
  // Q as B-operand: n = l15 -> q, k = quad*8+j -> d
  const h8 qf0 = *(const h8*)(Qp + (size_t)(q0 + l15) * HDn + quad * 8);
  const h8 qf1 = *(const h8*)(Qp + (size_t)(q0 + l15) * HDn + 32 + quad * 8);

  const int kbase = g * (Sn / 2);
  const float* mrow = mask + ((size_t)b * Sn + q0 + l15) * Sn + kbase;

  float m_run = -INFINITY, l_part = 0.f;  // l lane-partial; quad-reduced at end
  f4 o_acc[4];
#pragma unroll
  for (int nt = 0; nt < 4; ++nt) {
    f4 zz = {0.f, 0.f, 0.f, 0.f};
    o_acc[nt] = zz;
  }

  _Float16* Kg = smem + g * (64 * LDP);
  _Float16* Vg = smem + (2 + g) * (64 * LDP);
  _Float16* Pw = &Pl[(w * 16) * LDP];

  const int tg = t & 255;  // staging index within group (4 waves = 256 threads)
  const int srow = tg >> 3, sc8 = (tg & 7) * 8;        // K/V chunk 0 geometry
  const int srow1 = (tg + 256) >> 3, sc81 = ((tg + 256) & 7) * 8;  // chunk 1

  constexpr int NT = (Sn / 2) / 64;  // 16 tiles per group

  // ---- register prefetch buffers ----
  uint4 kreg0, kreg1, vreg0, vreg1;
  float4 mreg[4];
  auto kv_issue = [&](int kt) {
    kreg0 = *(const uint4*)(Kp + (size_t)(kbase + kt * 64 + srow) * HDn + sc8);
    vreg0 = *(const uint4*)(Vp + (size_t)srow * Sn + kbase + kt * 64 + sc8);
    kreg1 = *(const uint4*)(Kp + (size_t)(kbase + kt * 64 + srow1) * HDn + sc81);
    vreg1 = *(const uint4*)(Vp + (size_t)srow1 * Sn + kbase + kt * 64 + sc81);
  };
  auto m_issue = [&](int kt) {
#pragma unroll
    for (int ks = 0; ks < 4; ++ks)
      mreg[ks] = *(const float4*)(mrow + kt * 64 + ks * 16 + quad * 4);
  };

  kv_issue(0);
  m_issue(0);

  for (int kt = 0; kt < NT; ++kt) {
    __syncthreads();  // all waves done reading previous tile's LDS
    // regs -> LDS (vmcnt waits on loads issued one full tile ago)
    *(uint4*)&Kg[srow * LDP + sc8] = kreg0;
    *(uint4*)&Vg[srow * LDP + sc8] = vreg0;
    *(uint4*)&Kg[srow1 * LDP + sc81] = kreg1;
    *(uint4*)&Vg[srow1 * LDP + sc81] = vreg1;
    __syncthreads();  // tile ready
    const int nx = (kt + 1 < NT) ? kt + 1 : kt;
    kv_issue(nx);     // prefetch next tile; lands during this tile's compute

    // ---- S^T = K Q^T: rows = keys (quad*4+r), cols = q (l15) ----
    f4 s[4];
#pragma unroll
    for (int ks = 0; ks < 4; ++ks) {
      const h8 kf0 = *(const h8*)&Kg[(ks * 16 + l15) * LDP + quad * 8];
      const h8 kf1 = *(const h8*)&Kg[(ks * 16 + l15) * LDP + 32 + quad * 8];
      f4 a = {0.f, 0.f, 0.f, 0.f};
      a = MFMA16(kf0, qf0, a);
      a = MFMA16(kf1, qf1, a);
#pragma unroll
      for (int r = 0; r < 4; ++r)
        s[ks][r] = fmaf(((const float*)&mreg[ks])[r], LOG2E, a[r]);  // log2 dom
    }
    m_issue(nx);      // mreg consumed above; prefetch next tile's mask

    // ---- per-lane online softmax (exp2 domain); l stays lane-partial ----
    float mx = s[0][0];
#pragma unroll
    for (int ks = 0; ks < 4; ++ks)
#pragma unroll
      for (int r = 0; r < 4; ++r) mx = fmaxf(mx, s[ks][r]);
    mx = fmaxf(mx, __shfl_xor(mx, 16));
    mx = fmaxf(mx, __shfl_xor(mx, 32));
    const float nm = fmaxf(m_run, mx);
    const float alpha = EXP2F(m_run - nm);
    m_run = nm;
    float sm = 0.f;
#pragma unroll
    for (int ks = 0; ks < 4; ++ks)
#pragma unroll
      for (int r = 0; r < 4; ++r) {
        s[ks][r] = EXP2F(s[ks][r] - nm);
        sm += s[ks][r];
      }
    l_part = l_part * alpha + sm;
#pragma unroll
    for (int nt = 0; nt < 4; ++nt)
#pragma unroll
      for (int r = 0; r < 4; ++r) o_acc[nt][r] *= alpha;

    // ---- P^T packed write: Pw[q=l15][key], b64 stores (wave-private) ----
#pragma unroll
    for (int ks = 0; ks < 4; ++ks) {
      h4 pv;
#pragma unroll
      for (int r = 0; r < 4; ++r) pv[r] = (_Float16)s[ks][r];
      *(h4*)&Pw[l15 * LDP + ks * 16 + quad * 4] = pv;
    }
    // in-wave DS ordering -> no barrier (validated R4)

    // ---- U^T += V^T P^T (unnormalized) ----
#pragma unroll
    for (int kk = 0; kk < 64; kk += 32) {
      const h8 pf = *(const h8*)&Pw[l15 * LDP + kk + quad * 8];
#pragma unroll
      for (int nt = 0; nt < 4; ++nt) {
        const h8 vf = *(const h8*)&Vg[(nt * 16 + l15) * LDP + kk + quad * 8];
        o_acc[nt] = MFMA16(vf, pf, o_acc[nt]);
      }
    }
  }

  // ---- quad-reduce l (deferred from the loop) ----
  l_part += __shfl_xor(l_part, 16);
  l_part += __shfl_xor(l_part, 32);

  // ---- flash combine across the two key halves (pair w <-> w+4) ----
  __syncthreads();  // all main-loop smem reads done; reuse smem as fp32 area
  float* Uex = (float*)smem;            // [pair][q=16][stride 72] fp32
  float* mex = Uex + 4 * 16 * LDP;      // 4*16*72 = 4608 floats
  float* lex = mex + 64;
  if (g == 1) {
#pragma unroll
    for (int nt = 0; nt < 4; ++nt)
      *(f4*)&Uex[wq * 16 * LDP + l15 * LDP + nt * 16 + quad * 4] = o_acc[nt];
    if (quad == 0) {
      mex[wq * 16 + l15] = m_run;
      lex[wq * 16 + l15] = l_part;
    }
  }
  __syncthreads();
  if (g == 0) {
    const float m1 = mex[wq * 16 + l15];
    const float l1 = lex[wq * 16 + l15];
    const float mm = fmaxf(m_run, m1);
    const float f0 = EXP2F(m_run - mm);
    const float f1 = EXP2F(m1 - mm);
    const float rl = 1.0f / (f0 * l_part + f1 * l1);
#pragma unroll
    for (int nt = 0; nt < 4; ++nt) {
      const f4 Ur = *(const f4*)&Uex[wq * 16 * LDP + l15 * LDP + nt * 16 + quad * 4];
      h4 ov;
#pragma unroll
      for (int r = 0; r < 4; ++r)
        ov[r] = (_Float16)((o_acc[nt][r] * f0 + Ur[r] * f1) * rl);
      *(h4*)&Pw[l15 * LDP + nt * 16 + quad * 4] = ov;  // Ob[q_local][d]
    }
    // wave-private transpose -> coalesced stores
    const int qr = lane >> 2;            // 0..15
    const int seg = (lane & 3) * 16;     // 0,16,32,48
    _Float16* dst = out + ((size_t)b * Sn + q0 + qr) * Dn + h * 64 + seg;
    *(uint4*)dst = *(const uint4*)&Pw[qr * LDP + seg];
    *(uint4*)(dst + 8) = *(const uint4*)&Pw[qr * LDP + seg + 8];
  }
}

// ------------------------------ launch -------------------------------------
extern "C" void kernel_launch(void* const* d_in, const int* in_sizes, int n_in,
                              void* d_out, int out_size, void* d_ws, size_t ws_size,
                              hipStream_t stream) {
  const float* q = (const float*)d_in[0];
  const float* k = (const float*)d_in[1];
  const float* v = (const float*)d_in[2];
  const float* mask = (const float*)d_in[3];
  const float* WQ = (const float*)d_in[4];
  const float* bQ = (const float*)d_in[5];
  const float* WK = (const float*)d_in[6];
  const float* bK = (const float*)d_in[7];
  const float* WV = (const float*)d_in[8];
  const float* bV = (const float*)d_in[9];
  const float* WO = (const float*)d_in[10];
  const float* bO = (const float*)d_in[11];

  _Float16* ws = (_Float16*)d_ws;
  const size_t MD = (size_t)Mn * Dn;   // 4.19M elems
  const size_t DD = (size_t)Dn * Dn;   // 1.05M
  _Float16* qh  = ws;
  _Float16* kh  = ws + MD;
  _Float16* vh  = ws + 2 * MD;
  _Float16* WQh = ws + 3 * MD;
  _Float16* WKh = WQh + DD;
  _Float16* WVh = WKh + DD;
  _Float16* WOh = WVh + DD;
  _Float16* Qh  = ws + 3 * MD + 4 * DD;
  _Float16* Kh  = Qh + MD;
  _Float16* Vt  = Kh + MD;
  _Float16* AO  = qh;  // qh dead after QKV gemm

  CvtJobs cj;
  cj.src[0] = q;  cj.dst[0] = qh;  cj.n4[0] = (int)(MD / 4);
  cj.src[1] = k;  cj.dst[1] = kh;  cj.n4[1] = (int)(MD / 4);
  cj.src[2] = v;  cj.dst[2] = vh;  cj.n4[2] = (int)(MD / 4);
  cj.src[3] = WQ; cj.dst[3] = WQh; cj.n4[3] = (int)(DD / 4);
  cj.src[4] = WK; cj.dst[4] = WKh; cj.n4[4] = (int)(DD / 4);
  cj.src[5] = WV; cj.dst[5] = WVh; cj.n4[5] = (int)(DD / 4);
  cj.src[6] = WO; cj.dst[6] = WOh; cj.n4[6] = (int)(DD / 4);
  cvt_kernel<<<1024, 256, 0, stream>>>(cj);

  QkvArgs ga;
  ga.X[0] = qh; ga.W[0] = WQh; ga.bias[0] = bQ; ga.out[0] = Qh;
  ga.X[1] = kh; ga.W[1] = WKh; ga.bias[1] = bK; ga.out[1] = Kh;
  ga.X[2] = vh; ga.W[2] = WVh; ga.bias[2] = bV; ga.out[2] = Vt;
  gemm_qkv<<<dim3(Nn / 128, Mn / 128, 3), 256, 0, stream>>>(ga);

  attn_kernel<<<dim3(Sn / 64, Bn * Hn), 512, 0, stream>>>(Qh, Kh, Vt, mask, AO);

  gemm_o<<<dim3(Nn / 128, Mn / 128), 256, 0, stream>>>(AO, WOh, bO, (float*)d_out);
}